// Round 14
// baseline (300.303 us; speedup 1.0000x reference)
//
#include <hip/hip_runtime.h>
#include <math.h>

#define Bn 512
#define Sn 1024
#define Tn 48
#define NSEG 32
#define SEGLEN 32

typedef _Float16 h2 __attribute__((ext_vector_type(2)));
typedef _Float16 h4 __attribute__((ext_vector_type(4)));
typedef float    f4 __attribute__((ext_vector_type(4)));

static constexpr float LOG2E = 1.4426950408889634f;
static constexpr float LN2f  = 0.6931471805599453f;

// Unconditional: __has_builtin for amdgcn builtins returns 0 in the host pass.
#define MFMA16(A, B, C) __builtin_amdgcn_mfma_f32_16x16x16f16((A), (B), (C), 0, 0, 0)

__device__ __forceinline__ h2 hmax2(h2 a, h2 b) {
#if __has_builtin(__builtin_elementwise_max)
  return __builtin_elementwise_max(a, b);
#else
  h2 r;
  r[0] = a[0] > b[0] ? a[0] : b[0];
  r[1] = a[1] > b[1] ? a[1] : b[1];
  return r;
#endif
}
__device__ __forceinline__ h2 cvt2(float a, float b) {
  return __builtin_bit_cast(h2, __builtin_amdgcn_cvt_pkrtz(a, b));
}
__device__ __forceinline__ h4 mkh4(h2 lo, h2 hi) {
  return __builtin_shufflevector(lo, hi, 0, 1, 2, 3);
}
__device__ __forceinline__ h2 loh(h4 v) { return __builtin_shufflevector(v, v, 0, 1); }
__device__ __forceinline__ h2 hih(h4 v) { return __builtin_shufflevector(v, v, 2, 3); }

// Memory-bound pregen: ehat[b][s][k] = f16(2^(em*log2e - 6)) (RTN converts).
__global__ __launch_bounds__(256) void ehgen(const float* __restrict__ em,
                                             _Float16* __restrict__ out) {
  const size_t total = (size_t)Bn * Sn * Tn;
  const size_t i = ((size_t)blockIdx.x * 256 + threadIdx.x) * 8;
  if (i >= total) return;
  const f4 a = *(const f4*)(em + i);
  const f4 b = *(const f4*)(em + i + 4);
  h4 o1, o2;
  #pragma unroll
  for (int j = 0; j < 4; ++j) {
    o1[j] = (_Float16)__builtin_amdgcn_exp2f(fmaf(a[j], LOG2E, -6.0f));
    o2[j] = (_Float16)__builtin_amdgcn_exp2f(fmaf(b[j], LOG2E, -6.0f));
  }
  *(h4*)(out + i) = o1;
  *(h4*)(out + i + 4) = o2;
}

// Segment-parallel CRF forward, TWO interleaved chains per wave.
// Rounds 9+13 proved dur*MfmaUtil invariant (~103us) at ~4 waves/SIMD
// (register-bound): the step boundary (MFMA -> cvt tail -> next MFMA)
// serializes each wave to ~12% duty. Wave wid evolves segments 2wid and
// 2wid+1 (32 steps each) interleaved: chain B's MFMAs are independent of
// chain A's tail -> fills the pipe bubbles. Total MFMA work unchanged.
// Combine: 32-turn register-resident pipeline over lwbuf (256 B LDS).
template <bool PRE>
__global__ __launch_bounds__(1024, 2)
void crf_fwd_seg(const float* __restrict__ em,
                 const float* __restrict__ mask,
                 const float* __restrict__ trans,
                 const float* __restrict__ startt,
                 const float* __restrict__ endt,
                 const _Float16* __restrict__ eh16,
                 float* __restrict__ den_out)
{
  const int b   = blockIdx.x;
  const int tid = threadIdx.x;
  const int wid = tid >> 6;     // wave id 0..15 -> segments 2wid, 2wid+1
  const int l   = tid & 63;
  const int c16 = l & 15;       // column within a 16-col tile
  const int g   = l >> 4;       // row/k group: rows 4g..4g+3

  __shared__ float lwbuf[64];   // running log2 state for the combine

  const float*    __restrict__ emb = em + (size_t)b * Sn * Tn;
  const float*    __restrict__ mkb = mask + (size_t)b * Sn;
  const _Float16* __restrict__ ehL = PRE ? (eh16 + (size_t)b * Sn * Tn + 4 * g) : nullptr;
  const float*    __restrict__ emL = emb + 4 * g;

  // ---- static A fragments + global trans max (log2 domain) ----
  h4 Afr[3][3];
  float mtg;
  {
    float tl[3][3][4];
    float mt = -1e30f;
    #pragma unroll
    for (int rt = 0; rt < 3; ++rt)
      #pragma unroll
      for (int kt = 0; kt < 3; ++kt) {
        const f4 t4 = *(const f4*)(trans + (16 * rt + c16) * Tn + 16 * kt + 4 * g);
        #pragma unroll
        for (int i = 0; i < 4; ++i) {
          const float v = t4[i] * LOG2E;
          tl[rt][kt][i] = v;
          mt = fmaxf(mt, v);
        }
      }
    #pragma unroll
    for (int off = 1; off < 64; off <<= 1) mt = fmaxf(mt, __shfl_xor(mt, off));
    mtg = mt;
    #pragma unroll
    for (int rt = 0; rt < 3; ++rt)
      #pragma unroll
      for (int kt = 0; kt < 3; ++kt) {
        h4 r;
        #pragma unroll
        for (int i = 0; i < 4; ++i)
          r[i] = (_Float16)__builtin_amdgcn_exp2f(tl[rt][kt][i] - mtg);
        Afr[rt][kt] = r;
      }
  }

  // ---- two chain states: W = I (48x48, f16 tiles), per-column shift Mc ----
  h4 BfA[3][3], BfB[3][3];
  float McA[3] = {0.f, 0.f, 0.f}, McB[3] = {0.f, 0.f, 0.f};
  float cntA = 0.f, cntB = 0.f;
  #pragma unroll
  for (int kt = 0; kt < 3; ++kt)
    #pragma unroll
    for (int ct = 0; ct < 3; ++ct) {
      h4 r;
      #pragma unroll
      for (int i = 0; i < 4; ++i)
        r[i] = (_Float16)(((16 * kt + 4 * g + i) == (16 * ct + c16)) ? 1.0f : 0.0f);
      BfA[kt][ct] = r;
      BfB[kt][ct] = r;
    }

  auto loadEH = [&](int s, h4& x, h4& y, h4& z) {
    if constexpr (PRE) {
      const _Float16* p = ehL + (size_t)s * Tn;
      x = *(const h4*)(p);
      y = *(const h4*)(p + 16);
      z = *(const h4*)(p + 32);
    } else {
      const float* p = emL + (size_t)s * Tn;
      const f4 a = *(const f4*)(p);
      const f4 b2 = *(const f4*)(p + 16);
      const f4 c2 = *(const f4*)(p + 32);
      f4 ea, eb2, ec;
      #pragma unroll
      for (int i = 0; i < 4; ++i) {
        ea[i]  = __builtin_amdgcn_exp2f(fmaf(a[i],  LOG2E, -6.0f));
        eb2[i] = __builtin_amdgcn_exp2f(fmaf(b2[i], LOG2E, -6.0f));
        ec[i]  = __builtin_amdgcn_exp2f(fmaf(c2[i], LOG2E, -6.0f));
      }
      x = mkh4(cvt2(ea[0], ea[1]), cvt2(ea[2], ea[3]));
      y = mkh4(cvt2(eb2[0], eb2[1]), cvt2(eb2[2], eb2[3]));
      z = mkh4(cvt2(ec[0], ec[1]), cvt2(ec[2], ec[3]));
    }
  };

  // One recurrence step on state Bf/Mc/cnt. Loads its own eh (issued before
  // the MFMAs -> L2 latency hidden). APPLY: multiply by exact 2^-sh (derived
  // from shv at use) and account the shift.
  auto STEP = [&](auto& Bf, auto& Mc, float& cnt, int s, bool APPLY,
                  const float (&shv)[3]) {
    const float mkval = mkb[s];
    h4 e0, e1, e2;
    loadEH(s, e0, e1, e2);
    if (__int_as_float(__builtin_amdgcn_readfirstlane(__float_as_int(mkval))) > 0.0f) {
      f4 acc[3][3];
      #pragma unroll
      for (int rt = 0; rt < 3; ++rt)
        #pragma unroll
        for (int ct = 0; ct < 3; ++ct) acc[rt][ct] = f4{0.f, 0.f, 0.f, 0.f};
      #pragma unroll
      for (int kt = 0; kt < 3; ++kt)
        #pragma unroll
        for (int rt = 0; rt < 3; ++rt)
          #pragma unroll
          for (int ct = 0; ct < 3; ++ct)
            acc[rt][ct] = MFMA16(Afr[rt][kt], Bf[kt][ct], acc[rt][ct]);
      float scv[3];
      if (APPLY) {
        #pragma unroll
        for (int ct = 0; ct < 3; ++ct)
          scv[ct] = __int_as_float((127 - (int)shv[ct]) << 23);  // exact 2^-sh
      }
      const h4 ehv[3] = {e0, e1, e2};
      #pragma unroll
      for (int rt = 0; rt < 3; ++rt) {
        const h2 elo = loh(ehv[rt]);
        const h2 ehi = hih(ehv[rt]);
        #pragma unroll
        for (int ct = 0; ct < 3; ++ct) {
          f4 a = acc[rt][ct];
          if (APPLY) {
            a[0] *= scv[ct]; a[1] *= scv[ct]; a[2] *= scv[ct]; a[3] *= scv[ct];
          }
          const h2 lo = cvt2(a[0], a[1]) * elo;
          const h2 hi = cvt2(a[2], a[3]) * ehi;
          Bf[rt][ct] = mkh4(lo, hi);
        }
      }
      if (APPLY) { Mc[0] += shv[0]; Mc[1] += shv[1]; Mc[2] += shv[2]; }
      cnt += 1.0f;
    }
  };

  auto MEASURE = [&](auto& Bf, float (&sh)[3]) {
    #pragma unroll
    for (int ct = 0; ct < 3; ++ct) {
      h2 m = loh(Bf[0][ct]);
      m = hmax2(m, hih(Bf[0][ct]));
      m = hmax2(m, loh(Bf[1][ct]));
      m = hmax2(m, hih(Bf[1][ct]));
      m = hmax2(m, loh(Bf[2][ct]));
      m = hmax2(m, hih(Bf[2][ct]));
      m = hmax2(m, __builtin_bit_cast(h2, __shfl_xor(__builtin_bit_cast(int, m), 16)));
      m = hmax2(m, __builtin_bit_cast(h2, __shfl_xor(__builtin_bit_cast(int, m), 32)));
      const float mf = fmaxf((float)m[0], (float)m[1]);
      int eb = ((__float_as_int(mf) >> 23) & 0xff) - 127;
      eb = eb < -15 ? -15 : (eb > 15 ? 15 : eb);
      sh[ct] = (float)eb;
    }
  };

  // chain A = segment 2wid (steps sA..sA+31), chain B = segment 2wid+1
  // (steps sB..sB+31; wid 15's chain B ends at 1023 -> 31 steps, guarded).
  float shPA[3] = {0.f, 0.f, 0.f}, shAA[3] = {0.f, 0.f, 0.f};
  float shPB[3] = {0.f, 0.f, 0.f}, shAB[3] = {0.f, 0.f, 0.f};
  int a = 1 + 2 * SEGLEN * wid;
  int bs = a + SEGLEN;
  #pragma unroll 1
  for (int c = 0; c < 7; ++c) {   // 28 steps per chain, branch-free interleave
    STEP(BfA, McA, cntA, a + 0, false, shPA);
    STEP(BfB, McB, cntB, bs + 0, false, shPB);
    STEP(BfA, McA, cntA, a + 1, true,  shPA);  MEASURE(BfA, shAA);
    STEP(BfB, McB, cntB, bs + 1, true,  shPB); MEASURE(BfB, shAB);
    STEP(BfA, McA, cntA, a + 2, false, shPA);
    STEP(BfB, McB, cntB, bs + 2, false, shPB);
    STEP(BfA, McA, cntA, a + 3, true,  shAA);  MEASURE(BfA, shPA);
    STEP(BfB, McB, cntB, bs + 3, true,  shAB); MEASURE(BfB, shPB);
    a += 4; bs += 4;
  }
  // epilogue chunk: A steps a..a+3 always; B steps guarded (wid15: 3 steps)
  STEP(BfA, McA, cntA, a + 0, false, shPA);
  if (bs + 0 < Sn) STEP(BfB, McB, cntB, bs + 0, false, shPB);
  STEP(BfA, McA, cntA, a + 1, true, shPA);  MEASURE(BfA, shAA);
  if (bs + 1 < Sn) { STEP(BfB, McB, cntB, bs + 1, true, shPB); MEASURE(BfB, shAB); }
  STEP(BfA, McA, cntA, a + 2, false, shPA);
  if (bs + 2 < Sn) STEP(BfB, McB, cntB, bs + 2, false, shPB);
  STEP(BfA, McA, cntA, a + 3, true, shAA);
  if (bs + 3 < Sn) STEP(BfB, McB, cntB, bs + 3, true, shAB);

  // ---- register-resident combine: 32 turns, wave t>>1 applies chain t&1 ----
  const float addcA = (mtg + 6.0f) * cntA;
  const float addcB = (mtg + 6.0f) * cntB;
  if (wid == 0 && l < Tn) lwbuf[l] = (startt[l] + emb[l]) * LOG2E;
  __syncthreads();

  auto APPLYM = [&](auto& Bf, auto& Mc, float addc) {
    const float u0 = lwbuf[c16]      + Mc[0] + addc;
    const float u1 = lwbuf[16 + c16] + Mc[1] + addc;
    const float u2 = lwbuf[32 + c16] + Mc[2] + addc;
    float um = fmaxf(u0, fmaxf(u1, u2));
    #pragma unroll
    for (int off = 1; off < 64; off <<= 1) um = fmaxf(um, __shfl_xor(um, off));
    const float p0 = __builtin_amdgcn_exp2f(u0 - um);
    const float p1 = __builtin_amdgcn_exp2f(u1 - um);
    const float p2 = __builtin_amdgcn_exp2f(u2 - um);
    float rs[3][4];
    #pragma unroll
    for (int kt = 0; kt < 3; ++kt)
      #pragma unroll
      for (int i = 0; i < 4; ++i) {
        float v = (float)Bf[kt][0][i] * p0;
        v = fmaf((float)Bf[kt][1][i], p1, v);
        v = fmaf((float)Bf[kt][2][i], p2, v);
        #pragma unroll
        for (int off = 1; off < 16; off <<= 1) v += __shfl_xor(v, off);
        rs[kt][i] = v;
      }
    if (c16 == 0) {
      #pragma unroll
      for (int kt = 0; kt < 3; ++kt)
        #pragma unroll
        for (int i = 0; i < 4; ++i)
          lwbuf[16 * kt + 4 * g + i] = um + __builtin_amdgcn_logf(rs[kt][i]);
    }
  };

  #pragma unroll 1
  for (int t = 0; t < NSEG; ++t) {
    if ((t & 1) == 0) {
      if (wid == (t >> 1)) APPLYM(BfA, McA, addcA);
    } else {
      if (wid == (t >> 1)) APPLYM(BfB, McB, addcB);
    }
    __syncthreads();
  }

  // ---- final: den = lse_j(lw[j] + end2[j]) * ln2 ----
  if (wid == 0) {
    float v = (l < Tn) ? lwbuf[l] + endt[l] * LOG2E : -INFINITY;
    float mv = v;
    #pragma unroll
    for (int off = 32; off; off >>= 1) mv = fmaxf(mv, __shfl_xor(mv, off));
    float zz = (l < Tn) ? __builtin_amdgcn_exp2f(v - mv) : 0.f;
    #pragma unroll
    for (int off = 32; off; off >>= 1) zz += __shfl_xor(zz, off);
    if (l == 0) den_out[b] = (mv + __builtin_amdgcn_logf(zz)) * LN2f;
  }
}

// Numerator: no recurrence -> fully parallel gather+reduce. One block per batch.
__global__ __launch_bounds__(256) void crf_numer(
    const float* __restrict__ em, const int* __restrict__ tags,
    const float* __restrict__ mask, const float* __restrict__ trans,
    const float* __restrict__ startt, const float* __restrict__ endt,
    float* __restrict__ num_out)
{
  const int b = blockIdx.x, t = threadIdx.x;
  const int*   tgb = tags + (size_t)b * Sn;
  const float* mkb = mask + (size_t)b * Sn;
  const float* emb = em + (size_t)b * Sn * Tn;

  const int s0 = t * 4;
  const int4 tg = *(const int4*)(tgb + s0);
  const f4   mk = *(const f4*)(mkb + s0);
  const int  tprev = (t == 0) ? 0 : tgb[s0 - 1];
  const int  tgarr[5] = {tprev, tg.x, tg.y, tg.z, tg.w};

  float acc  = 0.0f;
  float msum = mk[0] + mk[1] + mk[2] + mk[3];
  #pragma unroll
  for (int i = 0; i < 4; ++i) {
    const int s = s0 + i;
    if (s >= 1)
      acc += mk[i] * (emb[(size_t)s * Tn + tgarr[i + 1]] +
                      trans[tgarr[i + 1] * Tn + tgarr[i]]);
  }
  #pragma unroll
  for (int off = 32; off; off >>= 1) {
    acc  += __shfl_xor(acc, off);
    msum += __shfl_xor(msum, off);
  }
  __shared__ float ra[4], rm[4];
  if ((t & 63) == 0) { ra[t >> 6] = acc; rm[t >> 6] = msum; }
  __syncthreads();
  if (t == 0) {
    const float a = ra[0] + ra[1] + ra[2] + ra[3];
    const float m = rm[0] + rm[1] + rm[2] + rm[3];
    int last = (int)(m + 0.5f) - 1;
    if (last < 0) last = 0;
    const int lt = tgb[last];
    const int t0 = tgb[0];
    num_out[b] = startt[t0] + emb[t0] + a + endt[lt];
  }
}

__global__ __launch_bounds__(512) void reduce_loss(const float* __restrict__ den,
                                                   const float* __restrict__ num,
                                                   float* __restrict__ out) {
  __shared__ float red[8];
  const int t = threadIdx.x;
  float v = den[t] - num[t];
  #pragma unroll
  for (int off = 32; off; off >>= 1) v += __shfl_xor(v, off);
  if ((t & 63) == 0) red[t >> 6] = v;
  __syncthreads();
  if (t == 0) {
    float s = 0.f;
    #pragma unroll
    for (int wv = 0; wv < 8; ++wv) s += red[wv];
    out[0] = s * (1.0f / 512.0f);
  }
}

extern "C" void kernel_launch(void* const* d_in, const int* in_sizes, int n_in,
                              void* d_out, int out_size, void* d_ws, size_t ws_size,
                              hipStream_t stream) {
  const float* emissions = (const float*)d_in[0];
  const int*   tags      = (const int*)d_in[1];
  const float* mask      = (const float*)d_in[2];
  const float* trans     = (const float*)d_in[3];
  const float* startt    = (const float*)d_in[4];
  const float* endt      = (const float*)d_in[5];
  float* den_ws = (float*)d_ws;         // 512 floats
  float* num_ws = den_ws + Bn;          // 512 floats
  const size_t ehoff   = 4096;
  const size_t ehbytes = (size_t)Bn * Sn * Tn * sizeof(_Float16);
  _Float16* eh16 = (_Float16*)((char*)d_ws + ehoff);
  const bool pre = (ws_size >= ehoff + ehbytes);

  crf_numer<<<Bn, 256, 0, stream>>>(emissions, tags, mask, trans, startt, endt, num_ws);
  if (pre) {
    const int total8 = Bn * Sn * Tn / 8;
    ehgen<<<(total8 + 255) / 256, 256, 0, stream>>>(emissions, eh16);
    crf_fwd_seg<true><<<Bn, 1024, 0, stream>>>(emissions, mask, trans, startt, endt,
                                               eh16, den_ws);
  } else {
    crf_fwd_seg<false><<<Bn, 1024, 0, stream>>>(emissions, mask, trans, startt, endt,
                                                nullptr, den_ws);
  }
  reduce_loss<<<1, 512, 0, stream>>>(den_ws, num_ws, (float*)d_out);
}

// Round 15
// 240.125 us; speedup vs baseline: 1.2506x; 1.2506x over previous
//
#include <hip/hip_runtime.h>
#include <math.h>

#define Bn 512
#define Sn 1024
#define Tn 48
#define NSEG 8
#define SEGLEN 128

typedef _Float16 h2 __attribute__((ext_vector_type(2)));
typedef _Float16 h4 __attribute__((ext_vector_type(4)));
typedef float    f4 __attribute__((ext_vector_type(4)));

static constexpr float LOG2E = 1.4426950408889634f;
static constexpr float LN2f  = 0.6931471805599453f;

// Unconditional: __has_builtin for amdgcn builtins returns 0 in the host pass.
#define MFMA16(A, B, C) __builtin_amdgcn_mfma_f32_16x16x16f16((A), (B), (C), 0, 0, 0)

__device__ __forceinline__ h2 hmax2(h2 a, h2 b) {
#if __has_builtin(__builtin_elementwise_max)
  return __builtin_elementwise_max(a, b);
#else
  h2 r;
  r[0] = a[0] > b[0] ? a[0] : b[0];
  r[1] = a[1] > b[1] ? a[1] : b[1];
  return r;
#endif
}
__device__ __forceinline__ h2 cvt2(float a, float b) {
  return __builtin_bit_cast(h2, __builtin_amdgcn_cvt_pkrtz(a, b));
}
__device__ __forceinline__ h4 mkh4(h2 lo, h2 hi) {
  return __builtin_shufflevector(lo, hi, 0, 1, 2, 3);
}
__device__ __forceinline__ h2 loh(h4 v) { return __builtin_shufflevector(v, v, 0, 1); }
__device__ __forceinline__ h2 hih(h4 v) { return __builtin_shufflevector(v, v, 2, 3); }

// Memory-bound pregen: ehat[b][s][k] = f16(2^(em*log2e - 6)) (RTN converts).
__global__ __launch_bounds__(256) void ehgen(const float* __restrict__ em,
                                             _Float16* __restrict__ out) {
  const size_t total = (size_t)Bn * Sn * Tn;
  const size_t i = ((size_t)blockIdx.x * 256 + threadIdx.x) * 8;
  if (i >= total) return;
  const f4 a = *(const f4*)(em + i);
  const f4 b = *(const f4*)(em + i + 4);
  h4 o1, o2;
  #pragma unroll
  for (int j = 0; j < 4; ++j) {
    o1[j] = (_Float16)__builtin_amdgcn_exp2f(fmaf(a[j], LOG2E, -6.0f));
    o2[j] = (_Float16)__builtin_amdgcn_exp2f(fmaf(b[j], LOG2E, -6.0f));
  }
  *(h4*)(out + i) = o1;
  *(h4*)(out + i + 4) = o2;
}

// Segment-parallel CRF forward, TWO interleaved chains per wave, 256-thread
// blocks (4 waves). Round 14's lesson: a 1024-thread block forces 4 waves/SIMD
// -> 128-reg cap -> the 2nd chain spilled (WRITE_SIZE 150MB). At 256 threads
// the cap is 256 regs/wave: both chains fit, 2 waves/SIMD, and the compiler
// interleaves chain B's MFMAs under chain A's VALU/wait tail in-order.
// Wave w owns segments 2w (chain A) and 2w+1 (chain B), 128 steps each.
// Combine: 8-turn register-resident pipeline over lwbuf (256 B LDS).
template <bool PRE>
__global__ __launch_bounds__(256, 1)
void crf_fwd_seg(const float* __restrict__ em,
                 const float* __restrict__ mask,
                 const float* __restrict__ trans,
                 const float* __restrict__ startt,
                 const float* __restrict__ endt,
                 const _Float16* __restrict__ eh16,
                 float* __restrict__ den_out)
{
  const int b   = blockIdx.x;
  const int tid = threadIdx.x;
  const int wid = tid >> 6;     // wave id 0..3 -> segments 2wid, 2wid+1
  const int l   = tid & 63;
  const int c16 = l & 15;       // column within a 16-col tile
  const int g   = l >> 4;       // row/k group: rows 4g..4g+3

  __shared__ float lwbuf[64];   // running log2 state for the combine

  const float*    __restrict__ emb = em + (size_t)b * Sn * Tn;
  const float*    __restrict__ mkb = mask + (size_t)b * Sn;
  const _Float16* __restrict__ ehL = PRE ? (eh16 + (size_t)b * Sn * Tn + 4 * g) : nullptr;
  const float*    __restrict__ emL = emb + 4 * g;

  // ---- static A fragments + global trans max (log2 domain) ----
  h4 Afr[3][3];
  float mtg;
  {
    float tl[3][3][4];
    float mt = -1e30f;
    #pragma unroll
    for (int rt = 0; rt < 3; ++rt)
      #pragma unroll
      for (int kt = 0; kt < 3; ++kt) {
        const f4 t4 = *(const f4*)(trans + (16 * rt + c16) * Tn + 16 * kt + 4 * g);
        #pragma unroll
        for (int i = 0; i < 4; ++i) {
          const float v = t4[i] * LOG2E;
          tl[rt][kt][i] = v;
          mt = fmaxf(mt, v);
        }
      }
    #pragma unroll
    for (int off = 1; off < 64; off <<= 1) mt = fmaxf(mt, __shfl_xor(mt, off));
    mtg = mt;
    #pragma unroll
    for (int rt = 0; rt < 3; ++rt)
      #pragma unroll
      for (int kt = 0; kt < 3; ++kt) {
        h4 r;
        #pragma unroll
        for (int i = 0; i < 4; ++i)
          r[i] = (_Float16)__builtin_amdgcn_exp2f(tl[rt][kt][i] - mtg);
        Afr[rt][kt] = r;
      }
  }

  // ---- two chain states: W = I (48x48, f16 tiles), per-column shift Mc ----
  h4 BfA[3][3], BfB[3][3];
  float McA[3] = {0.f, 0.f, 0.f}, McB[3] = {0.f, 0.f, 0.f};
  float cntA = 0.f, cntB = 0.f;
  #pragma unroll
  for (int kt = 0; kt < 3; ++kt)
    #pragma unroll
    for (int ct = 0; ct < 3; ++ct) {
      h4 r;
      #pragma unroll
      for (int i = 0; i < 4; ++i)
        r[i] = (_Float16)(((16 * kt + 4 * g + i) == (16 * ct + c16)) ? 1.0f : 0.0f);
      BfA[kt][ct] = r;
      BfB[kt][ct] = r;
    }

  auto loadEH = [&](int s, h4& x, h4& y, h4& z) {
    if constexpr (PRE) {
      const _Float16* p = ehL + (size_t)s * Tn;
      x = *(const h4*)(p);
      y = *(const h4*)(p + 16);
      z = *(const h4*)(p + 32);
    } else {
      const float* p = emL + (size_t)s * Tn;
      const f4 a = *(const f4*)(p);
      const f4 b2 = *(const f4*)(p + 16);
      const f4 c2 = *(const f4*)(p + 32);
      f4 ea, eb2, ec;
      #pragma unroll
      for (int i = 0; i < 4; ++i) {
        ea[i]  = __builtin_amdgcn_exp2f(fmaf(a[i],  LOG2E, -6.0f));
        eb2[i] = __builtin_amdgcn_exp2f(fmaf(b2[i], LOG2E, -6.0f));
        ec[i]  = __builtin_amdgcn_exp2f(fmaf(c2[i], LOG2E, -6.0f));
      }
      x = mkh4(cvt2(ea[0], ea[1]), cvt2(ea[2], ea[3]));
      y = mkh4(cvt2(eb2[0], eb2[1]), cvt2(eb2[2], eb2[3]));
      z = mkh4(cvt2(ec[0], ec[1]), cvt2(ec[2], ec[3]));
    }
  };

  // One recurrence step. mk value passed in registers (chunk-prefetched).
  auto STEP = [&](auto& Bf, auto& Mc, float& cnt, int s, float mkval,
                  bool APPLY, const float (&shv)[3]) {
    h4 e0, e1, e2;
    loadEH(s, e0, e1, e2);
    if (__int_as_float(__builtin_amdgcn_readfirstlane(__float_as_int(mkval))) > 0.0f) {
      f4 acc[3][3];
      #pragma unroll
      for (int rt = 0; rt < 3; ++rt)
        #pragma unroll
        for (int ct = 0; ct < 3; ++ct) acc[rt][ct] = f4{0.f, 0.f, 0.f, 0.f};
      #pragma unroll
      for (int kt = 0; kt < 3; ++kt)
        #pragma unroll
        for (int rt = 0; rt < 3; ++rt)
          #pragma unroll
          for (int ct = 0; ct < 3; ++ct)
            acc[rt][ct] = MFMA16(Afr[rt][kt], Bf[kt][ct], acc[rt][ct]);
      float scv[3];
      if (APPLY) {
        #pragma unroll
        for (int ct = 0; ct < 3; ++ct)
          scv[ct] = __int_as_float((127 - (int)shv[ct]) << 23);  // exact 2^-sh
      }
      const h4 ehv[3] = {e0, e1, e2};
      #pragma unroll
      for (int rt = 0; rt < 3; ++rt) {
        const h2 elo = loh(ehv[rt]);
        const h2 ehi = hih(ehv[rt]);
        #pragma unroll
        for (int ct = 0; ct < 3; ++ct) {
          f4 a = acc[rt][ct];
          if (APPLY) {
            a[0] *= scv[ct]; a[1] *= scv[ct]; a[2] *= scv[ct]; a[3] *= scv[ct];
          }
          const h2 lo = cvt2(a[0], a[1]) * elo;
          const h2 hi = cvt2(a[2], a[3]) * ehi;
          Bf[rt][ct] = mkh4(lo, hi);
        }
      }
      if (APPLY) { Mc[0] += shv[0]; Mc[1] += shv[1]; Mc[2] += shv[2]; }
      cnt += 1.0f;
    }
  };

  auto MEASURE = [&](auto& Bf, float (&sh)[3]) {
    #pragma unroll
    for (int ct = 0; ct < 3; ++ct) {
      h2 m = loh(Bf[0][ct]);
      m = hmax2(m, hih(Bf[0][ct]));
      m = hmax2(m, loh(Bf[1][ct]));
      m = hmax2(m, hih(Bf[1][ct]));
      m = hmax2(m, loh(Bf[2][ct]));
      m = hmax2(m, hih(Bf[2][ct]));
      m = hmax2(m, __builtin_bit_cast(h2, __shfl_xor(__builtin_bit_cast(int, m), 16)));
      m = hmax2(m, __builtin_bit_cast(h2, __shfl_xor(__builtin_bit_cast(int, m), 32)));
      const float mf = fmaxf((float)m[0], (float)m[1]);
      int eb = ((__float_as_int(mf) >> 23) & 0xff) - 127;
      eb = eb < -15 ? -15 : (eb > 15 ? 15 : eb);
      sh[ct] = (float)eb;
    }
  };

  // chain A = segment 2wid (steps sA..sA+127), chain B = segment 2wid+1
  // (steps sB..sB+127; wid 3's chain B ends at 1023 -> 127 steps, guarded).
  float shPA[3] = {0.f, 0.f, 0.f}, shAA[3] = {0.f, 0.f, 0.f};
  float shPB[3] = {0.f, 0.f, 0.f}, shAB[3] = {0.f, 0.f, 0.f};
  int sA = 1 + 2 * SEGLEN * wid;
  int sB = sA + SEGLEN;
  f4 mkA = *(const f4*)(mkb + sA);
  f4 mkB = *(const f4*)(mkb + sB);
  f4 mknA, mknB;
  #pragma unroll 1
  for (int c = 0; c < 31; ++c) {   // 124 steps per chain
    const int pfA = (c + 1 < 31) ? sA + 4 : sA;  // in-bounds prefetch
    const int pfB = (c + 1 < 31) ? sB + 4 : sB;  // max 1017 for wid 3
    mknA = *(const f4*)(mkb + pfA);
    mknB = *(const f4*)(mkb + pfB);
    STEP(BfA, McA, cntA, sA + 0, mkA[0], false, shPA);
    STEP(BfB, McB, cntB, sB + 0, mkB[0], false, shPB);
    STEP(BfA, McA, cntA, sA + 1, mkA[1], true,  shPA);  MEASURE(BfA, shAA);
    STEP(BfB, McB, cntB, sB + 1, mkB[1], true,  shPB);  MEASURE(BfB, shAB);
    STEP(BfA, McA, cntA, sA + 2, mkA[2], false, shPA);
    STEP(BfB, McB, cntB, sB + 2, mkB[2], false, shPB);
    STEP(BfA, McA, cntA, sA + 3, mkA[3], true,  shAA);  MEASURE(BfA, shPA);
    STEP(BfB, McB, cntB, sB + 3, mkB[3], true,  shAB);  MEASURE(BfB, shPB);
    mkA = mknA; mkB = mknB;
    sA += 4; sB += 4;
  }
  // epilogue: steps 124..127 of each chain; scalar masks; B guarded (wid 3).
  STEP(BfA, McA, cntA, sA + 0, mkb[sA + 0], false, shPA);
  if (sB + 0 < Sn) STEP(BfB, McB, cntB, sB + 0, mkb[sB + 0], false, shPB);
  STEP(BfA, McA, cntA, sA + 1, mkb[sA + 1], true, shPA);  MEASURE(BfA, shAA);
  if (sB + 1 < Sn) { STEP(BfB, McB, cntB, sB + 1, mkb[sB + 1], true, shPB); MEASURE(BfB, shAB); }
  STEP(BfA, McA, cntA, sA + 2, mkb[sA + 2], false, shPA);
  if (sB + 2 < Sn) STEP(BfB, McB, cntB, sB + 2, mkb[sB + 2], false, shPB);
  STEP(BfA, McA, cntA, sA + 3, mkb[sA + 3], true, shAA);
  if (sB + 3 < Sn) STEP(BfB, McB, cntB, sB + 3, mkb[sB + 3], true, shAB);

  // ---- register-resident combine: 8 turns, wave t>>1 applies chain t&1 ----
  const float addcA = (mtg + 6.0f) * cntA;
  const float addcB = (mtg + 6.0f) * cntB;
  if (wid == 0 && l < Tn) lwbuf[l] = (startt[l] + emb[l]) * LOG2E;
  __syncthreads();

  auto APPLYM = [&](auto& Bf, auto& Mc, float addc) {
    const float u0 = lwbuf[c16]      + Mc[0] + addc;
    const float u1 = lwbuf[16 + c16] + Mc[1] + addc;
    const float u2 = lwbuf[32 + c16] + Mc[2] + addc;
    float um = fmaxf(u0, fmaxf(u1, u2));
    #pragma unroll
    for (int off = 1; off < 64; off <<= 1) um = fmaxf(um, __shfl_xor(um, off));
    const float p0 = __builtin_amdgcn_exp2f(u0 - um);
    const float p1 = __builtin_amdgcn_exp2f(u1 - um);
    const float p2 = __builtin_amdgcn_exp2f(u2 - um);
    float rs[3][4];
    #pragma unroll
    for (int kt = 0; kt < 3; ++kt)
      #pragma unroll
      for (int i = 0; i < 4; ++i) {
        float v = (float)Bf[kt][0][i] * p0;
        v = fmaf((float)Bf[kt][1][i], p1, v);
        v = fmaf((float)Bf[kt][2][i], p2, v);
        #pragma unroll
        for (int off = 1; off < 16; off <<= 1) v += __shfl_xor(v, off);
        rs[kt][i] = v;
      }
    if (c16 == 0) {
      #pragma unroll
      for (int kt = 0; kt < 3; ++kt)
        #pragma unroll
        for (int i = 0; i < 4; ++i)
          lwbuf[16 * kt + 4 * g + i] = um + __builtin_amdgcn_logf(rs[kt][i]);
    }
  };

  #pragma unroll 1
  for (int t = 0; t < NSEG; ++t) {
    if ((t & 1) == 0) {
      if (wid == (t >> 1)) APPLYM(BfA, McA, addcA);
    } else {
      if (wid == (t >> 1)) APPLYM(BfB, McB, addcB);
    }
    __syncthreads();
  }

  // ---- final: den = lse_j(lw[j] + end2[j]) * ln2 ----
  if (wid == 0) {
    float v = (l < Tn) ? lwbuf[l] + endt[l] * LOG2E : -INFINITY;
    float mv = v;
    #pragma unroll
    for (int off = 32; off; off >>= 1) mv = fmaxf(mv, __shfl_xor(mv, off));
    float zz = (l < Tn) ? __builtin_amdgcn_exp2f(v - mv) : 0.f;
    #pragma unroll
    for (int off = 32; off; off >>= 1) zz += __shfl_xor(zz, off);
    if (l == 0) den_out[b] = (mv + __builtin_amdgcn_logf(zz)) * LN2f;
  }
}

// Numerator: no recurrence -> fully parallel gather+reduce. One block per batch.
__global__ __launch_bounds__(256) void crf_numer(
    const float* __restrict__ em, const int* __restrict__ tags,
    const float* __restrict__ mask, const float* __restrict__ trans,
    const float* __restrict__ startt, const float* __restrict__ endt,
    float* __restrict__ num_out)
{
  const int b = blockIdx.x, t = threadIdx.x;
  const int*   tgb = tags + (size_t)b * Sn;
  const float* mkb = mask + (size_t)b * Sn;
  const float* emb = em + (size_t)b * Sn * Tn;

  const int s0 = t * 4;
  const int4 tg = *(const int4*)(tgb + s0);
  const f4   mk = *(const f4*)(mkb + s0);
  const int  tprev = (t == 0) ? 0 : tgb[s0 - 1];
  const int  tgarr[5] = {tprev, tg.x, tg.y, tg.z, tg.w};

  float acc  = 0.0f;
  float msum = mk[0] + mk[1] + mk[2] + mk[3];
  #pragma unroll
  for (int i = 0; i < 4; ++i) {
    const int s = s0 + i;
    if (s >= 1)
      acc += mk[i] * (emb[(size_t)s * Tn + tgarr[i + 1]] +
                      trans[tgarr[i + 1] * Tn + tgarr[i]]);
  }
  #pragma unroll
  for (int off = 32; off; off >>= 1) {
    acc  += __shfl_xor(acc, off);
    msum += __shfl_xor(msum, off);
  }
  __shared__ float ra[4], rm[4];
  if ((t & 63) == 0) { ra[t >> 6] = acc; rm[t >> 6] = msum; }
  __syncthreads();
  if (t == 0) {
    const float a = ra[0] + ra[1] + ra[2] + ra[3];
    const float m = rm[0] + rm[1] + rm[2] + rm[3];
    int last = (int)(m + 0.5f) - 1;
    if (last < 0) last = 0;
    const int lt = tgb[last];
    const int t0 = tgb[0];
    num_out[b] = startt[t0] + emb[t0] + a + endt[lt];
  }
}

__global__ __launch_bounds__(512) void reduce_loss(const float* __restrict__ den,
                                                   const float* __restrict__ num,
                                                   float* __restrict__ out) {
  __shared__ float red[8];
  const int t = threadIdx.x;
  float v = den[t] - num[t];
  #pragma unroll
  for (int off = 32; off; off >>= 1) v += __shfl_xor(v, off);
  if ((t & 63) == 0) red[t >> 6] = v;
  __syncthreads();
  if (t == 0) {
    float s = 0.f;
    #pragma unroll
    for (int wv = 0; wv < 8; ++wv) s += red[wv];
    out[0] = s * (1.0f / 512.0f);
  }
}

extern "C" void kernel_launch(void* const* d_in, const int* in_sizes, int n_in,
                              void* d_out, int out_size, void* d_ws, size_t ws_size,
                              hipStream_t stream) {
  const float* emissions = (const float*)d_in[0];
  const int*   tags      = (const int*)d_in[1];
  const float* mask      = (const float*)d_in[2];
  const float* trans     = (const float*)d_in[3];
  const float* startt    = (const float*)d_in[4];
  const float* endt      = (const float*)d_in[5];
  float* den_ws = (float*)d_ws;         // 512 floats
  float* num_ws = den_ws + Bn;          // 512 floats
  const size_t ehoff   = 4096;
  const size_t ehbytes = (size_t)Bn * Sn * Tn * sizeof(_Float16);
  _Float16* eh16 = (_Float16*)((char*)d_ws + ehoff);
  const bool pre = (ws_size >= ehoff + ehbytes);

  crf_numer<<<Bn, 256, 0, stream>>>(emissions, tags, mask, trans, startt, endt, num_ws);
  if (pre) {
    const int total8 = Bn * Sn * Tn / 8;
    ehgen<<<(total8 + 255) / 256, 256, 0, stream>>>(emissions, eh16);
    crf_fwd_seg<true><<<Bn, 256, 0, stream>>>(emissions, mask, trans, startt, endt,
                                              eh16, den_ws);
  } else {
    crf_fwd_seg<false><<<Bn, 256, 0, stream>>>(emissions, mask, trans, startt, endt,
                                               nullptr, den_ws);
  }
  reduce_loss<<<1, 512, 0, stream>>>(den_ws, num_ws, (float*)d_out);
}